// Round 15
// baseline (275.246 us; speedup 1.0000x reference)
//
#include <hip/hip_runtime.h>

// OrthoLinear: out[32,8192] = x @ (dequant int4 W)^T + alpha * x @ CSR^T
// R13 post-mortem: dense < 78us (fell out of top-5; top-5 is now the harness's
// 536MB ws-poison fill at 78us). Cross-round accounting: ~160us/iter harness
// overhead; our kernels ~100us (dense ~60-70, sparse ~20, prep+reduce ~10).
// R14: (1) drop x_lo (single-bf16 x): dot-err std ~0.007, max ~0.05 << 0.1775
//      threshold; halves dense MFMAs, staging 16->12KB/step, 5->6 blocks/CU.
//      (2) fold reduce into sparse (same-stream ordering makes dense partials
//      visible): out = alpha*sum + sum_g part[g], one dispatch fewer.
// R15: resubmit unchanged (R14 bench never ran: GPUAcquisitionTimeout).

#define IN_F 8192
#define OUT_F 8192
#define NROW 32
#define KSPLIT 8
#define KSEG (IN_F / KSPLIT)   // 1024
#define KS 64                  // k per stage step
#define NSTEP (KSEG / KS)      // 16
#define PK_TILE 8192           // 64 rows x 128 B packed bytes per step
#define X_TILE 4096            // 32 rows x 128 B bf16 per step
#define BUF_SZ (PK_TILE + X_TILE)  // 12288
#define SLICE (NROW * OUT_F)   // 1MB partial slice

typedef __attribute__((ext_vector_type(8))) short short8v;
typedef __attribute__((ext_vector_type(4))) float f32x4;

union Frag {
  int4 v;
  unsigned int u[4];
  short8v s;
};

__device__ __forceinline__ unsigned int cvt_pk_bf16(float lo, float hi) {
  unsigned int r;
  asm("v_cvt_pk_bf16_f32 %0, %1, %2" : "=v"(r) : "v"(lo), "v"(hi));
  return r;
}

__device__ __forceinline__ unsigned short f2bf(float f) {
  unsigned int u = __float_as_uint(f);
  u += 0x7FFFu + ((u >> 16) & 1u);
  return (unsigned short)(u >> 16);
}

// prep: x -> x_hi (bf16, row-major) + xTb (bf16, [k][n] 64B rows, coalesced
// via LDS tile). x_lo dropped (R14).
__global__ __launch_bounds__(256) void prep_kernel(
    const float* __restrict__ x, unsigned short* __restrict__ x_hi,
    unsigned short* __restrict__ xTb) {
  __shared__ unsigned short T[64 * 33];
  int tid = threadIdx.x;
  int k0 = blockIdx.x * 64;
  int kk = tid & 63;
  int ng = tid >> 6;
#pragma unroll
  for (int p = 0; p < 8; ++p) {
    int n = p * 4 + ng;
    int idx = n * IN_F + k0 + kk;
    unsigned short h = f2bf(x[idx]);
    x_hi[idx] = h;
    T[kk * 33 + n] = h;
  }
  __syncthreads();
  int kr = tid >> 2, q = tid & 3;
  unsigned int s0 = T[kr * 33 + q * 8 + 0], s1 = T[kr * 33 + q * 8 + 1];
  unsigned int s2 = T[kr * 33 + q * 8 + 2], s3 = T[kr * 33 + q * 8 + 3];
  unsigned int s4 = T[kr * 33 + q * 8 + 4], s5 = T[kr * 33 + q * 8 + 5];
  unsigned int s6 = T[kr * 33 + q * 8 + 6], s7 = T[kr * 33 + q * 8 + 7];
  int4 wv;
  wv.x = (int)(s0 | (s1 << 16));
  wv.y = (int)(s2 | (s3 << 16));
  wv.z = (int)(s4 | (s5 << 16));
  wv.w = (int)(s6 | (s7 << 16));
  ((int4*)xTb)[(size_t)(k0 + kr) * 4 + q] = wv;
}

// dense: global_load_lds staging, double-buffered 24KB LDS, 16 K-steps,
// XOR-swizzle (row&7)<<4 both sides. Single-bf16 x (R14).
__global__ __launch_bounds__(256) void dense_kernel(
    const int* __restrict__ packed, const float* __restrict__ scales,
    const unsigned short* __restrict__ x_hi, float* __restrict__ part) {
  __shared__ char lds[2][BUF_SZ];
  int tid = threadIdx.x;
  int lane = tid & 63;
  int w = tid >> 6;
  int og = blockIdx.x >> 3;
  int g = blockIdx.x & 7;
  int lo16 = lane & 15;
  int lhi = lane >> 4;

  // staging sources (pre-swizzled so the linear LDS write lands swizzled)
  int L0 = tid * 16;                       // linear byte in round-0 region
  int pr0 = L0 >> 7;                       // packed tile row 0..31
  int pb0 = (L0 & 127) ^ ((pr0 & 7) << 4); // swizzled source byte
  const char* pkB = (const char*)packed;   // packed row = 16384 B
  const char* psrc0 = pkB + (size_t)(og * 64 + pr0) * 16384 + g * 2048 + pb0;
  const char* psrc1 = pkB + (size_t)(og * 64 + pr0 + 32) * 16384 + g * 2048 + pb0;
  int xr = tid >> 3;                       // x tile row 0..31
  int xb = ((tid & 7) * 16) ^ ((xr & 7) << 4);
  const char* xhsrc = (const char*)x_hi + (size_t)xr * (IN_F * 2) + g * 2048 + xb;
  int woff = w * 1024;                     // wave-uniform LDS dest offset

#define STAGE(s, b)                                                          \
  {                                                                          \
    int so_ = (s) * 128;                                                     \
    __builtin_amdgcn_global_load_lds((const unsigned int*)(psrc0 + so_),     \
        (unsigned int*)(&lds[b][0] + woff), 16, 0, 0);                       \
    __builtin_amdgcn_global_load_lds((const unsigned int*)(psrc1 + so_),     \
        (unsigned int*)(&lds[b][4096] + woff), 16, 0, 0);                    \
    __builtin_amdgcn_global_load_lds((const unsigned int*)(xhsrc + so_),     \
        (unsigned int*)(&lds[b][PK_TILE] + woff), 16, 0, 0);                 \
  }

  f32x4 acc0 = {0.f, 0.f, 0.f, 0.f};
  f32x4 acc1 = {0.f, 0.f, 0.f, 0.f};
  int prow = w * 16 + lo16;               // packed tile row this lane reads
  int pswz = (prow & 7) << 4;
  int xswz = (lo16 & 7) << 4;             // rows lo16 and lo16+16: same &7

#define COMPCHUNK(b, cp)                                                      \
  {                                                                           \
    int pby = (cp) * 64 + 16 * lhi;                                           \
    Frag bb, a0h, a1h;                                                        \
    bb.v = *(const int4*)&lds[b][prow * 128 + (pby ^ pswz)];                  \
    a0h.v = *(const int4*)&lds[b][PK_TILE + lo16 * 128 + (pby ^ xswz)];       \
    a1h.v = *(const int4*)&lds[b][PK_TILE + (lo16 + 16) * 128 + (pby ^ xswz)]; \
    Frag bf;                                                                  \
    bf.u[0] = cvt_pk_bf16((float)(bb.v.x & 15) - 8.0f, (float)(bb.v.x >> 4) - 8.0f); \
    bf.u[1] = cvt_pk_bf16((float)(bb.v.y & 15) - 8.0f, (float)(bb.v.y >> 4) - 8.0f); \
    bf.u[2] = cvt_pk_bf16((float)(bb.v.z & 15) - 8.0f, (float)(bb.v.z >> 4) - 8.0f); \
    bf.u[3] = cvt_pk_bf16((float)(bb.v.w & 15) - 8.0f, (float)(bb.v.w >> 4) - 8.0f); \
    acc0 = __builtin_amdgcn_mfma_f32_16x16x32_bf16(a0h.s, bf.s, acc0, 0, 0, 0); \
    acc1 = __builtin_amdgcn_mfma_f32_16x16x32_bf16(a1h.s, bf.s, acc1, 0, 0, 0); \
  }

  STAGE(0, 0)
  for (int s = 0; s < NSTEP; ++s) {
    int b = s & 1;
    if (s + 1 < NSTEP) {
      STAGE(s + 1, (s + 1) & 1)
      asm volatile("s_waitcnt vmcnt(3)" ::: "memory");
    } else {
      asm volatile("s_waitcnt vmcnt(0)" ::: "memory");
    }
    __syncthreads();
    COMPCHUNK(b, 0)
    COMPCHUNK(b, 1)
    __syncthreads();
  }
#undef STAGE
#undef COMPCHUNK

  // partial store: part[g][m][o]  (C layout: col=lane&15 = o, row=lhi*4+r = m)
  int o = og * 64 + w * 16 + lo16;
  float sc = scales[o];
  float* ps = part + (size_t)g * SLICE;
#pragma unroll
  for (int r = 0; r < 4; ++r) {
    int m = lhi * 4 + r;
    ps[(size_t)m * OUT_F + o] = sc * acc0[r];
    ps[(size_t)(m + 16) * OUT_F + o] = sc * acc1[r];
  }
}

// sparse + final reduce (R14): wave computes alpha*sum for its row ro, then
// adds the 8 dense partials (visible: same-stream kernel ordering) and writes
// out directly.
__global__ __launch_bounds__(256) void sparse_kernel(
    const float* __restrict__ vals, const int* __restrict__ cols,
    const int* __restrict__ rptr, const float* __restrict__ alphap,
    const unsigned short* __restrict__ xTb, const float* __restrict__ part,
    float* __restrict__ out) {
  __shared__ float red[4][64 * 33];
  int tid = threadIdx.x;
  int lane = tid & 63;
  int w = tid >> 6;
  float alpha = alphap[0];
  float* R = red[w];
#pragma unroll 1
  for (int rr = 0; rr < 2; ++rr) {
    int ro = blockIdx.x * 8 + w * 2 + rr;
    int js = rptr[ro], je = rptr[ro + 1];
    float acc[32];
#pragma unroll
    for (int i = 0; i < 32; ++i) acc[i] = 0.f;

    int j = js + lane;
    float vc = 0.f;
    int cc = 0;
    if (j < je) { vc = vals[j]; cc = cols[j]; }
    while (j < je) {
      int jn = j + 64;
      float vn = 0.f;
      int cn = 0;
      if (jn < je) { vn = vals[jn]; cn = cols[jn]; }
      const int4* xp = (const int4*)(xTb + (size_t)cc * NROW);
      int4 q0 = xp[0], q1 = xp[1], q2 = xp[2], q3 = xp[3];
#define UNP(dw, base)                                                          \
  {                                                                            \
    unsigned int ud = (unsigned int)(dw);                                      \
    acc[base] = fmaf(vc, __uint_as_float(ud << 16), acc[base]);                \
    acc[base + 1] = fmaf(vc, __uint_as_float(ud & 0xFFFF0000u), acc[base + 1]); \
  }
      UNP(q0.x, 0) UNP(q0.y, 2) UNP(q0.z, 4) UNP(q0.w, 6)
      UNP(q1.x, 8) UNP(q1.y, 10) UNP(q1.z, 12) UNP(q1.w, 14)
      UNP(q2.x, 16) UNP(q2.y, 18) UNP(q2.z, 20) UNP(q2.w, 22)
      UNP(q3.x, 24) UNP(q3.y, 26) UNP(q3.z, 28) UNP(q3.w, 30)
#undef UNP
      j = jn;
      vc = vn;
      cc = cn;
    }
#pragma unroll
    for (int i = 0; i < 32; ++i) R[lane * 33 + i] = acc[i];
    int cidx = lane & 31;
    int h = lane >> 5;
    float sum = 0.f;
#pragma unroll
    for (int r2 = 0; r2 < 32; ++r2) sum += R[(h * 32 + r2) * 33 + cidx];
    sum += __shfl_xor(sum, 32, 64);
    if (lane < 32) {
      float t = alpha * sum;
      const float* pp = part + (size_t)lane * OUT_F + ro;
#pragma unroll
      for (int g2 = 0; g2 < 8; ++g2) t += pp[(size_t)g2 * SLICE];
      out[(size_t)lane * OUT_F + ro] = t;
    }
  }
}

extern "C" void kernel_launch(void* const* d_in, const int* in_sizes, int n_in,
                              void* d_out, int out_size, void* d_ws, size_t ws_size,
                              hipStream_t stream) {
  const float* x = (const float*)d_in[0];
  const int* packed = (const int*)d_in[1];
  const float* scales = (const float*)d_in[2];
  const float* vals = (const float*)d_in[3];
  const int* cols = (const int*)d_in[4];
  const int* rptr = (const int*)d_in[5];
  const float* alphap = (const float*)d_in[6];
  float* out = (float*)d_out;

  unsigned short* x_hi = (unsigned short*)d_ws;            // 512 KB
  unsigned short* xTb = x_hi + NROW * IN_F;                // 512 KB
  float* part = (float*)(xTb + NROW * IN_F);               // 8 x 1 MB

  prep_kernel<<<IN_F / 64, 256, 0, stream>>>(x, x_hi, xTb);
  dense_kernel<<<(OUT_F / 64) * KSPLIT, 256, 0, stream>>>(
      packed, scales, x_hi, part);
  sparse_kernel<<<OUT_F / 8, 256, 0, stream>>>(
      vals, cols, rptr, alphap, xTb, part, out);
}